// Round 1
// baseline (173.517 us; speedup 1.0000x reference)
//
#include <hip/hip_runtime.h>

// Multi-scale deformable attention forward.
// value:              (N, Lin, nH, D)        float32
// spatial_shapes:     (L, 2)                 int32 or int64 (runtime-detected)
// level_start_index:  (L,)                   int32 or int64 (runtime-detected)
// sampling_locations: (N, Lq, nH, L, P, 2)   float32
// attention_weights:  (N, Lq, nH, L, P)      float32
// out:                (N, Lq, nH*D)          float32
//
// Constants for this problem instance:
#define NH 8
#define DD 32
#define LL 4
#define PP 4

// Thread mapping: tid -> (n, q, h, c) with c in [0,8): float4 channel group.
// 8 consecutive threads cover one (n,q,h) sample unit -> each corner gather is
// a contiguous 128B read across the group (coalesced).
__global__ __launch_bounds__(256) void msda_fwd(
    const float* __restrict__ value,
    const int*   __restrict__ spatial_shapes,
    const int*   __restrict__ level_start,
    const float* __restrict__ sloc,
    const float* __restrict__ aw,
    float*       __restrict__ out,
    int N, int Lq, int Lin, int total)
{
    int tid = blockIdx.x * blockDim.x + threadIdx.x;
    if (tid >= total) return;

    const int c  = tid & 7;          // float4 group within D
    const int h  = (tid >> 3) & 7;   // head
    const int nq = tid >> 6;         // n*Lq + q
    // (n,q) split not needed separately except for value addressing:
    const int n  = nq / Lq;

    // --- metadata (uniform): detect int32 vs int64 layout ---
    // int64 little-endian of [[92,92],...] puts 0 at word index 1.
    const bool is64 = (spatial_shapes[1] == 0);
    int Hs[LL], Ws[LL], Ss[LL];
#pragma unroll
    for (int l = 0; l < LL; ++l) {
        if (is64) {
            Hs[l] = spatial_shapes[4 * l];
            Ws[l] = spatial_shapes[4 * l + 2];
            Ss[l] = level_start[2 * l];
        } else {
            Hs[l] = spatial_shapes[2 * l];
            Ws[l] = spatial_shapes[2 * l + 1];
            Ss[l] = level_start[l];
        }
    }

    const size_t nqh = (size_t)nq * NH + h;
    const float* __restrict__ loc_p = sloc + nqh * (LL * PP * 2);
    const float* __restrict__ aw_p  = aw   + nqh * (LL * PP);

    float4 acc = make_float4(0.f, 0.f, 0.f, 0.f);

#pragma unroll
    for (int l = 0; l < LL; ++l) {
        const int H = Hs[l];
        const int W = Ws[l];
        // base of this level's feature map for (n, head h, channel group c)
        const float* __restrict__ vb =
            value + (((size_t)n * Lin + Ss[l]) * NH + h) * DD + c * 4;
        const int pstride = NH * DD;   // floats per spatial position (=256)

#pragma unroll
        for (int p = 0; p < PP; ++p) {
            const int j = l * PP + p;
            const float x = loc_p[2 * j + 0] * (float)W - 0.5f;
            const float y = loc_p[2 * j + 1] * (float)H - 0.5f;
            const float w = aw_p[j];

            const float x0f = floorf(x);
            const float y0f = floorf(y);
            const int x0 = (int)x0f;
            const int y0 = (int)y0f;
            const int x1 = x0 + 1;
            const int y1 = y0 + 1;
            const float dx = x - x0f;
            const float dy = y - y0f;

            const bool vx0 = (x0 >= 0) && (x0 < W);
            const bool vx1 = (x1 >= 0) && (x1 < W);
            const bool vy0 = (y0 >= 0) && (y0 < H);
            const bool vy1 = (y1 >= 0) && (y1 < H);

            const int cx0 = min(max(x0, 0), W - 1);
            const int cx1 = min(max(x1, 0), W - 1);
            const int cy0 = min(max(y0, 0), H - 1);
            const int cy1 = min(max(y1, 0), H - 1);

            const float w00 = (1.f - dx) * (1.f - dy) * w * ((vx0 && vy0) ? 1.f : 0.f);
            const float w01 = dx         * (1.f - dy) * w * ((vx1 && vy0) ? 1.f : 0.f);
            const float w10 = (1.f - dx) * dy         * w * ((vx0 && vy1) ? 1.f : 0.f);
            const float w11 = dx         * dy         * w * ((vx1 && vy1) ? 1.f : 0.f);

            const float4 v00 = *(const float4*)(vb + (size_t)(cy0 * W + cx0) * pstride);
            const float4 v01 = *(const float4*)(vb + (size_t)(cy0 * W + cx1) * pstride);
            const float4 v10 = *(const float4*)(vb + (size_t)(cy1 * W + cx0) * pstride);
            const float4 v11 = *(const float4*)(vb + (size_t)(cy1 * W + cx1) * pstride);

            acc.x += w00 * v00.x + w01 * v01.x + w10 * v10.x + w11 * v11.x;
            acc.y += w00 * v00.y + w01 * v01.y + w10 * v10.y + w11 * v11.y;
            acc.z += w00 * v00.z + w01 * v01.z + w10 * v10.z + w11 * v11.z;
            acc.w += w00 * v00.w + w01 * v01.w + w10 * v10.w + w11 * v11.w;
        }
    }

    // out: (N, Lq, nH*D) -> flat index nqh*D + c*4
    *(float4*)(out + nqh * DD + c * 4) = acc;
}

extern "C" void kernel_launch(void* const* d_in, const int* in_sizes, int n_in,
                              void* d_out, int out_size, void* d_ws, size_t ws_size,
                              hipStream_t stream)
{
    const float* value = (const float*)d_in[0];
    const int*   ss    = (const int*)  d_in[1];
    const int*   lsi   = (const int*)  d_in[2];
    const float* sloc  = (const float*)d_in[3];
    const float* aw    = (const float*)d_in[4];
    float* out = (float*)d_out;

    const int N = 2;
    // aw elements = N*Lq*NH*LL*PP
    const int Lq  = in_sizes[4] / (N * NH * LL * PP);
    const int Lin = in_sizes[0] / (N * NH * DD);

    const int total  = N * Lq * NH * 8;   // 8 float4 groups per (n,q,h)
    const int block  = 256;
    const int grid   = (total + block - 1) / block;

    msda_fwd<<<grid, block, 0, stream>>>(value, ss, lsi, sloc, aw, out,
                                         N, Lq, Lin, total);
}